// Round 4
// baseline (3233.572 us; speedup 1.0000x reference)
//
#include <hip/hip_runtime.h>
#include <math.h>

#define NND 420
#define MAXE 5120
#define MAXS 65536

// output layout (float element offsets)
#define OFF_X    ((size_t)0)
#define OFF_RI   ((size_t)25600)
#define OFF_RO   ((size_t)(25600 + 335544320))
#define OFF_SUY  ((size_t)671114240)
#define OFF_SIDS ((size_t)671179776)
#define OFF_NIDX ((size_t)671310848)
#define OFF_EIDS ((size_t)671315968)

typedef float f4 __attribute__((ext_vector_type(4)));

static __device__ __forceinline__ float f32(double d) { return (float)d; }

// cross-phase edge features (written and read within the single mono block;
// __syncthreads() is a block-wide global+LDS fence, so this is race-free)
__device__ float g_dxn[MAXE], g_dyn[MAXE], g_dzn[MAXE], g_iop[MAXE], g_ioc[MAXE];
__device__ int   g_keep[MAXE], g_istrue[MAXE];

// ---------------- kSid: default super_ids = -2 (mono overwrites kept slots)
__global__ __launch_bounds__(256) void kSid(float* __restrict__ out) {
    int i = blockIdx.x * 256 + threadIdx.x;     // 32768 float4s = 131072 floats
    const f4 m = {-2.f, -2.f, -2.f, -2.f};
    ((f4*)(out + OFF_SIDS))[i] = m;
}

// ---------------- kMono: everything except the big zero-fill. ONE block.
__global__ __launch_bounds__(1024) void kMono(const float* __restrict__ ev,
                                              float* __restrict__ out) {
    __shared__ float s_r[NND], s_phi[NND], s_z[NND], s_st[NND], s_trk[NND], s_io[NND];
    __shared__ int   s_nscan[NND];
    __shared__ int   s_estart[NND + 1];
    __shared__ short s_ei[MAXE], s_ej[MAXE];
    __shared__ int   s_cnt[MAXE];
    __shared__ int   s_off2[MAXE];
    __shared__ int   s_part[1024];
    __shared__ int   s_ne;

    const float PI_F  = f32(3.141592653589793);
    const float TPI_F = f32(6.283185307179586);
    const float LO1 = -3.15f, SPAN1 = 3.15f + 3.15f;   // exact f32 of C_HI-C_LO
    const float LO2 = -2386.0f, SPAN2 = 4772.0f;
    const float SPAN0 = 312.0f;

    const int t = threadIdx.x;

    // ---- P0: node features
    float stv = 0.0f;
    if (t < NND) {
        float x = ev[t * 7 + 1], y = ev[t * 7 + 2];
        s_r[t]   = sqrtf(__fadd_rn(__fmul_rn(x, x), __fmul_rn(y, y)));
        s_phi[t] = atan2f(x, y);               // reference: arctan2(x, y)
        s_z[t]   = ev[t * 7 + 3];
        stv      = ev[t * 7 + 4];
        s_st[t]  = stv;
        s_trk[t] = ev[t * 7 + 5];
        s_io[t]  = ev[t * 7 + 6];
    }
    __syncthreads();

    // ---- P0b: per-node edge counts + inclusive scan + ordered edge list
    int cnt = 0;
    if (t < NND) {
        float target = stv + 1.0f;
        for (int j = 0; j < NND; ++j) cnt += (s_st[j] == target) ? 1 : 0;
        s_nscan[t] = cnt;
    }
    __syncthreads();
    for (int off = 1; off < NND; off <<= 1) {
        int v = 0;
        if (t < NND && t >= off) v = s_nscan[t - off];
        __syncthreads();
        if (t < NND) s_nscan[t] += v;
        __syncthreads();
    }
    if (t < NND) {
        int incl = s_nscan[t];
        int excl = incl - cnt;
        s_estart[t] = excl > MAXE ? MAXE : excl;
        int k = excl;
        float target = stv + 1.0f;
        for (int j = 0; j < NND; ++j) {
            if (s_st[j] == target) {
                if (k < MAXE) { s_ei[k] = (short)t; s_ej[k] = (short)j; }
                ++k;
            }
        }
        if (t == NND - 1) {
            int ne = incl > MAXE ? MAXE : incl;
            s_ne = ne;
            s_estart[NND] = ne;
        }
    }
    __syncthreads();
    const int ne = s_ne;

    // ---- P1: per-edge features + small outputs (5 edges per thread)
    for (int k = t; k < MAXE; k += 1024) {
        bool valid = (k < ne);
        int i = valid ? (int)s_ei[k] : 0;
        int j = valid ? (int)s_ej[k] : 0;

        float phip = s_phi[i], phic = s_phi[j];
        float zp = s_z[i], zc = s_z[j];
        float rp = s_r[i], rc = s_r[j];
        float iop = s_io[i], ioc = s_io[j];
        int istrue = (s_trk[i] == s_trk[j]) ? 1 : 0;

        float d = __fsub_rn(phic, phip);
        if (d >  PI_F) d = __fsub_rn(d, TPI_F);
        if (d < -PI_F) d = __fadd_rn(d, TPI_F);

        float dzv = __fsub_rn(zc, zp);
        float dxv = __fsub_rn(rc, rp);
        float dxn = __fdiv_rn(__fmul_rn(2.0f, dxv), SPAN0);
        float dyn = __fdiv_rn(__fmul_rn(2.0f, d),   SPAN1);
        float dzn = __fdiv_rn(__fmul_rn(2.0f, dzv), SPAN2);

        bool keep = valid && (dyn > -10.0f) && (dyn < 10.0f)
                          && (dzn > -10.0f) && (dzn < 10.0f);

        float ypn = __fsub_rn(__fdiv_rn(__fmul_rn(2.0f, __fsub_rn(phip, LO1)), SPAN1), 1.0f);
        float ycn = __fsub_rn(__fdiv_rn(__fmul_rn(2.0f, __fsub_rn(phic, LO1)), SPAN1), 1.0f);
        float zpn = __fsub_rn(__fdiv_rn(__fmul_rn(2.0f, __fsub_rn(zp, LO2)), SPAN2), 1.0f);
        float zcn = __fsub_rn(__fdiv_rn(__fmul_rn(2.0f, __fsub_rn(zc, LO2)), SPAN2), 1.0f);
        float ez  = __fdiv_rn(__fadd_rn(s_st[i], 1.0f), 35.0f);

        size_t oX = OFF_X + (size_t)k * 5;
        out[oX + 0] = keep ? ypn : 0.0f;
        out[oX + 1] = keep ? ycn : 0.0f;
        out[oX + 2] = keep ? zpn : 0.0f;
        out[oX + 3] = keep ? zcn : 0.0f;
        out[oX + 4] = keep ? ez  : 0.0f;

        out[OFF_NIDX + (size_t)k] = keep ? (float)k : -1.0f;
        size_t oE = OFF_EIDS + (size_t)k * 3;
        out[oE + 0] = keep ? iop : -1.0f;
        out[oE + 1] = keep ? ioc : -1.0f;
        out[oE + 2] = keep ? (float)k : -1.0f;

        g_dxn[k] = dxn; g_dyn[k] = dyn; g_dzn[k] = dzn;
        g_iop[k] = iop; g_ioc[k] = ioc;
        g_keep[k] = keep ? 1 : 0; g_istrue[k] = istrue;
    }
    __syncthreads();   // global + LDS fence within block

    // ---- P2: wave-per-a counts of kept super-edges
    const int w = t >> 6, lane = t & 63;
    for (int a = w; a < MAXE; a += 16) {
        int c = 0;
        if (a < ne && g_keep[a]) {          // wave-uniform condition
            int jn = (int)s_ej[a];
            int b0 = s_estart[jn], b1 = s_estart[jn + 1];
            float ioca = g_ioc[a];
            float a0 = g_dxn[a], a1 = g_dyn[a], a2 = g_dzn[a];
            for (int cs = b0; cs < b1; cs += 64) {
                int b = cs + lane;
                bool pred = false;
                if (b < b1 && g_keep[b] && (g_iop[b] == ioca)) {
                    float d0 = __fsub_rn(a0, g_dxn[b]);
                    float d1 = __fsub_rn(a1, g_dyn[b]);
                    float d2 = __fsub_rn(a2, g_dzn[b]);
                    float wgt = sqrtf(__fadd_rn(__fadd_rn(__fmul_rn(d0, d0),
                                                          __fmul_rn(d1, d1)),
                                                __fmul_rn(d2, d2)));
                    pred = (wgt < 0.1f);
                }
                c += (int)__popcll(__ballot(pred));
            }
        }
        if (lane == 0) s_cnt[a] = c;
    }
    __syncthreads();

    // ---- P3: exclusive scan over 5120 counts (5 per thread + 1024-scan)
    int v5[5]; int ssum = 0;
#pragma unroll
    for (int q = 0; q < 5; ++q) { v5[q] = s_cnt[t * 5 + q]; ssum += v5[q]; }
    s_part[t] = ssum;
    __syncthreads();
    for (int off = 1; off < 1024; off <<= 1) {
        int x = (t >= off) ? s_part[t - off] : 0;
        __syncthreads();
        s_part[t] += x;
        __syncthreads();
    }
    int run = s_part[t] - ssum;
#pragma unroll
    for (int q = 0; q < 5; ++q) { s_off2[t * 5 + q] = run; run += v5[q]; }
    __syncthreads();

    // ---- P4: order-preserving emission (ballot-prefix within wave)
    for (int a = w; a < MAXE; a += 16) {
        if (!(a < ne && g_keep[a])) continue;    // wave-uniform
        int jn = (int)s_ej[a];
        int b0 = s_estart[jn], b1 = s_estart[jn + 1];
        float ioca = g_ioc[a];
        float a0 = g_dxn[a], a1 = g_dyn[a], a2 = g_dzn[a];
        int ia = g_istrue[a];
        int base = s_off2[a];
        for (int cs = b0; cs < b1; cs += 64) {
            int b = cs + lane;
            bool pred = false;
            if (b < b1 && g_keep[b] && (g_iop[b] == ioca)) {
                float d0 = __fsub_rn(a0, g_dxn[b]);
                float d1 = __fsub_rn(a1, g_dyn[b]);
                float d2 = __fsub_rn(a2, g_dzn[b]);
                float wgt = sqrtf(__fadd_rn(__fadd_rn(__fmul_rn(d0, d0),
                                                      __fmul_rn(d1, d1)),
                                            __fmul_rn(d2, d2)));
                pred = (wgt < 0.1f);
            }
            unsigned long long mask = __ballot(pred);
            if (pred) {
                int pos = base + (int)__popcll(mask & ((1ull << lane) - 1ull));
                if (pos < MAXS) {
                    out[OFF_SUY + (size_t)pos] = (ia && g_istrue[b]) ? 1.0f : 0.0f;
                    size_t os = OFF_SIDS + (size_t)pos * 2;
                    out[os + 0] = (float)b;    // su_iop = e_index[se]
                    out[os + 1] = (float)a;    // su_ioc = e_index[fi]
                    out[OFF_RI + (size_t)a * MAXS + (size_t)pos] = 1.0f;
                    out[OFF_RO + (size_t)b * MAXS + (size_t)pos] = 1.0f;
                }
            }
            base += (int)__popcll(mask);
        }
    }
}

extern "C" void kernel_launch(void* const* d_in, const int* in_sizes, int n_in,
                              void* d_out, int out_size, void* d_ws, size_t ws_size,
                              hipStream_t stream) {
    const float* ev = (const float*)d_in[0];
    float* out = (float*)d_out;

    // Runtime fill is at the write ceiling (6.1 TB/s measured) — use it.
    hipMemsetAsync(d_out, 0, (size_t)out_size * sizeof(float), stream);
    // Default super_ids = -2 everywhere; kMono overwrites the kept slots.
    hipLaunchKernelGGL(kSid, dim3((MAXS * 2 / 4) / 256), dim3(256), 0, stream, out);
    // Everything else in one launch.
    hipLaunchKernelGGL(kMono, dim3(1), dim3(1024), 0, stream, ev, out);
}

// Round 5
// 2923.126 us; speedup vs baseline: 1.1062x; 1.1062x over previous
//
#include <hip/hip_runtime.h>
#include <hip/hip_cooperative_groups.h>
#include <math.h>

namespace cg = cooperative_groups;

#define NND 420
#define MAXE 5120
#define MAXS 65536

// output layout (float element offsets)
#define OFF_X    ((size_t)0)
#define OFF_RI   ((size_t)25600)
#define OFF_RO   ((size_t)(25600 + 335544320))
#define OFF_SUY  ((size_t)671114240)
#define OFF_SIDS ((size_t)671179776)
#define OFF_NIDX ((size_t)671310848)
#define OFF_EIDS ((size_t)671315968)

typedef float f4 __attribute__((ext_vector_type(4)));

static __device__ __forceinline__ float f32(double d) { return (float)d; }

// cross-block state (visibility ordered by grid.sync's device-scope fences)
__device__ float g_phi[NND], g_z[NND], g_st[NND];
__device__ short g_ei[MAXE], g_ej[MAXE];
__device__ int   g_estart[NND + 1];
__device__ float g_dxn[MAXE], g_dyn[MAXE], g_dzn[MAXE], g_iop[MAXE], g_ioc[MAXE];
__device__ int   g_keep[MAXE], g_istrue[MAXE];
__device__ int   g_cnt2[MAXE], g_off2[MAXE];
__device__ int   g_ne;

#define GRID_BLOCKS 1024
#define NWAVES ((GRID_BLOCKS * 256) >> 6)   // 4096

__global__ __launch_bounds__(256, 4) void kCoop(const float* __restrict__ ev,
                                                float* __restrict__ out, int n4) {
    cg::grid_group grid = cg::this_grid();

    __shared__ float s_r[NND], s_phi[NND], s_z[NND], s_st[NND], s_trk[NND], s_io[NND];
    __shared__ int   s_scan[NND];            // counts -> exclusive offsets
    __shared__ short s_ei[MAXE], s_ej[MAXE];
    __shared__ int   s_part[256];

    const float PI_F  = f32(3.141592653589793);
    const float TPI_F = f32(6.283185307179586);
    const float LO1 = -3.15f, SPAN1 = 3.15f + 3.15f;   // exact f32 of C_HI-C_LO
    const float LO2 = -2386.0f, SPAN2 = 4772.0f;
    const float SPAN0 = 312.0f;

    const int t   = threadIdx.x;
    const int bid = blockIdx.x;

    // ================= Phase A: block 0 computes; blocks 1..N-1 fill 2.685 GB
    if (bid == 0) {
        for (int n = t; n < NND; n += 256) {
            float x = ev[n * 7 + 1], y = ev[n * 7 + 2];
            s_r[n]   = sqrtf(__fadd_rn(__fmul_rn(x, x), __fmul_rn(y, y)));
            s_phi[n] = atan2f(x, y);           // reference: arctan2(x, y)
            s_z[n]   = ev[n * 7 + 3];
            s_st[n]  = ev[n * 7 + 4];
            s_trk[n] = ev[n * 7 + 5];
            s_io[n]  = ev[n * 7 + 6];
        }
        __syncthreads();
        for (int i = t; i < NND; i += 256) {
            float target = s_st[i] + 1.0f;
            int c = 0;
            for (int j = 0; j < NND; ++j) c += (s_st[j] == target) ? 1 : 0;
            s_scan[i] = c;
        }
        __syncthreads();
        if (t == 0) {   // serial scan over 420 — ~µs, hidden under the fill
            int acc = 0;
            for (int i = 0; i < NND; ++i) {
                int c = s_scan[i];
                s_scan[i] = acc;                               // exclusive
                g_estart[i] = acc > MAXE ? MAXE : acc;
                acc += c;
            }
            g_estart[NND] = acc > MAXE ? MAXE : acc;
            g_ne = acc > MAXE ? MAXE : acc;
        }
        __syncthreads();
        for (int i = t; i < NND; i += 256) {   // ordered edge list
            float target = s_st[i] + 1.0f;
            int k = s_scan[i];
            for (int j = 0; j < NND; ++j) {
                if (s_st[j] == target) {
                    if (k < MAXE) { s_ei[k] = (short)i; s_ej[k] = (short)j; }
                    ++k;
                }
            }
        }
        __syncthreads();
        const int ne = g_ne;
        for (int k = t; k < MAXE; k += 256) {  // per-edge features -> globals
            bool valid = (k < ne);
            int i = valid ? (int)s_ei[k] : 0;
            int j = valid ? (int)s_ej[k] : 0;
            float phip = s_phi[i], phic = s_phi[j];
            float zp = s_z[i], zc = s_z[j];
            float rp = s_r[i], rc = s_r[j];

            float d = __fsub_rn(phic, phip);
            if (d >  PI_F) d = __fsub_rn(d, TPI_F);
            if (d < -PI_F) d = __fadd_rn(d, TPI_F);

            float dzv = __fsub_rn(zc, zp);
            float dxv = __fsub_rn(rc, rp);
            float dxn = __fdiv_rn(__fmul_rn(2.0f, dxv), SPAN0);
            float dyn = __fdiv_rn(__fmul_rn(2.0f, d),   SPAN1);
            float dzn = __fdiv_rn(__fmul_rn(2.0f, dzv), SPAN2);

            bool keep = valid && (dyn > -10.0f) && (dyn < 10.0f)
                              && (dzn > -10.0f) && (dzn < 10.0f);

            g_dxn[k] = dxn; g_dyn[k] = dyn; g_dzn[k] = dzn;
            g_iop[k] = s_io[i]; g_ioc[k] = s_io[j];
            g_keep[k] = keep ? 1 : 0;
            g_istrue[k] = (s_trk[i] == s_trk[j]) ? 1 : 0;
            g_ei[k] = valid ? s_ei[k] : (short)0;
            g_ej[k] = valid ? s_ej[k] : (short)0;
        }
        for (int n = t; n < NND; n += 256) {
            g_phi[n] = s_phi[n]; g_z[n] = s_z[n]; g_st[n] = s_st[n];
        }
    } else {
        // streaming fill: zeros everywhere, -2 in the super_ids float4 range
        const size_t LOq = OFF_SIDS >> 2;
        const size_t HIq = (OFF_SIDS + 2 * (size_t)MAXS) >> 2;
        f4* p = (f4*)out;
        const f4 z = {0.f, 0.f, 0.f, 0.f};
        const f4 m = {-2.f, -2.f, -2.f, -2.f};
        size_t i = (size_t)(bid - 1) * 256 + t;
        const size_t stride = (size_t)(GRID_BLOCKS - 1) * 256;
        for (; i < (size_t)n4; i += stride)
            p[i] = (i >= LOq && i < HIq) ? m : z;
    }
    grid.sync();

    // ================= Phase B1: wave-per-a counts + per-edge small outputs
    const int gtid = bid * 256 + t;
    const int wid = gtid >> 6, lane = gtid & 63;
    const int ne = g_ne;
    for (int a = wid; a < MAXE; a += NWAVES) {
        bool akeep = (a < ne) && (g_keep[a] != 0);   // wave-uniform
        int c = 0;
        float ioca = 0.f, a0 = 0.f, a1 = 0.f, a2 = 0.f;
        if (akeep) {
            int jn = (int)g_ej[a];
            int b0 = g_estart[jn], b1 = g_estart[jn + 1];
            ioca = g_ioc[a]; a0 = g_dxn[a]; a1 = g_dyn[a]; a2 = g_dzn[a];
            for (int cs = b0; cs < b1; cs += 64) {
                int b = cs + lane;
                bool pred = false;
                if (b < b1 && g_keep[b] && (g_iop[b] == ioca)) {
                    float d0 = __fsub_rn(a0, g_dxn[b]);
                    float d1 = __fsub_rn(a1, g_dyn[b]);
                    float d2 = __fsub_rn(a2, g_dzn[b]);
                    float w = sqrtf(__fadd_rn(__fadd_rn(__fmul_rn(d0, d0),
                                                        __fmul_rn(d1, d1)),
                                              __fmul_rn(d2, d2)));
                    pred = (w < 0.1f);
                }
                c += (int)__popcll(__ballot(pred));
            }
        }
        if (lane == 0) {
            g_cnt2[a] = c;
            if (akeep) {
                int i = (int)g_ei[a], j = (int)g_ej[a];
                float phip = g_phi[i], phic = g_phi[j];
                float zp = g_z[i], zc = g_z[j];
                float ypn = __fsub_rn(__fdiv_rn(__fmul_rn(2.0f, __fsub_rn(phip, LO1)), SPAN1), 1.0f);
                float ycn = __fsub_rn(__fdiv_rn(__fmul_rn(2.0f, __fsub_rn(phic, LO1)), SPAN1), 1.0f);
                float zpn = __fsub_rn(__fdiv_rn(__fmul_rn(2.0f, __fsub_rn(zp, LO2)), SPAN2), 1.0f);
                float zcn = __fsub_rn(__fdiv_rn(__fmul_rn(2.0f, __fsub_rn(zc, LO2)), SPAN2), 1.0f);
                float ez  = __fdiv_rn(__fadd_rn(g_st[i], 1.0f), 35.0f);
                size_t oX = OFF_X + (size_t)a * 5;
                out[oX + 0] = ypn; out[oX + 1] = ycn; out[oX + 2] = zpn;
                out[oX + 3] = zcn; out[oX + 4] = ez;          // !keep rows stay 0
                out[OFF_NIDX + (size_t)a] = (float)a;
                size_t oE = OFF_EIDS + (size_t)a * 3;
                out[oE + 0] = ioca == ioca ? g_iop[a] : g_iop[a];
                out[oE + 1] = g_ioc[a];
                out[oE + 2] = (float)a;
            } else {
                out[OFF_NIDX + (size_t)a] = -1.0f;
                size_t oE = OFF_EIDS + (size_t)a * 3;
                out[oE + 0] = -1.0f; out[oE + 1] = -1.0f; out[oE + 2] = -1.0f;
            }
        }
    }
    grid.sync();

    // ================= Phase B2: block 0 scans the 5120 counts
    if (bid == 0) {
        int v[20]; int ssum = 0;
#pragma unroll
        for (int q = 0; q < 20; ++q) { v[q] = g_cnt2[t * 20 + q]; ssum += v[q]; }
        s_part[t] = ssum;
        __syncthreads();
        for (int off = 1; off < 256; off <<= 1) {
            int x = (t >= off) ? s_part[t - off] : 0;
            __syncthreads();
            s_part[t] += x;
            __syncthreads();
        }
        int run = s_part[t] - ssum;
#pragma unroll
        for (int q = 0; q < 20; ++q) { g_off2[t * 20 + q] = run; run += v[q]; }
    }
    grid.sync();

    // ================= Phase B3: order-preserving emission
    for (int a = wid; a < MAXE; a += NWAVES) {
        if (!((a < ne) && (g_keep[a] != 0))) continue;   // wave-uniform
        int jn = (int)g_ej[a];
        int b0 = g_estart[jn], b1 = g_estart[jn + 1];
        float ioca = g_ioc[a];
        float a0 = g_dxn[a], a1 = g_dyn[a], a2 = g_dzn[a];
        int ia = g_istrue[a];
        int base = g_off2[a];
        for (int cs = b0; cs < b1; cs += 64) {
            int b = cs + lane;
            bool pred = false;
            if (b < b1 && g_keep[b] && (g_iop[b] == ioca)) {
                float d0 = __fsub_rn(a0, g_dxn[b]);
                float d1 = __fsub_rn(a1, g_dyn[b]);
                float d2 = __fsub_rn(a2, g_dzn[b]);
                float w = sqrtf(__fadd_rn(__fadd_rn(__fmul_rn(d0, d0),
                                                    __fmul_rn(d1, d1)),
                                          __fmul_rn(d2, d2)));
                pred = (w < 0.1f);
            }
            unsigned long long mask = __ballot(pred);
            if (pred) {
                int pos = base + (int)__popcll(mask & ((1ull << lane) - 1ull));
                if (pos < MAXS) {
                    out[OFF_SUY + (size_t)pos] = (ia && g_istrue[b]) ? 1.0f : 0.0f;
                    size_t os = OFF_SIDS + (size_t)pos * 2;
                    out[os + 0] = (float)b;   // su_iop = e_index[se]
                    out[os + 1] = (float)a;   // su_ioc = e_index[fi]
                    out[OFF_RI + (size_t)a * MAXS + (size_t)pos] = 1.0f;
                    out[OFF_RO + (size_t)b * MAXS + (size_t)pos] = 1.0f;
                }
            }
            base += (int)__popcll(mask);
        }
    }
}

extern "C" void kernel_launch(void* const* d_in, const int* in_sizes, int n_in,
                              void* d_out, int out_size, void* d_ws, size_t ws_size,
                              hipStream_t stream) {
    const float* ev = (const float*)d_in[0];
    float* out = (float*)d_out;
    int n4 = out_size / 4;   // 167,832,832 float4s

    void* args[] = { (void*)&ev, (void*)&out, (void*)&n4 };
    hipLaunchCooperativeKernel((const void*)kCoop, dim3(GRID_BLOCKS), dim3(256),
                               args, 0, stream);
}

// Round 6
// 2588.655 us; speedup vs baseline: 1.2491x; 1.1292x over previous
//
#include <hip/hip_runtime.h>
#include <math.h>

#define NND 420
#define MAXE 5120
#define MAXS 65536

// output layout (float element offsets)
#define OFF_X    ((size_t)0)
#define OFF_RI   ((size_t)25600)
#define OFF_RO   ((size_t)(25600 + 335544320))
#define OFF_SUY  ((size_t)671114240)
#define OFF_SIDS ((size_t)671179776)
#define OFF_NIDX ((size_t)671310848)
#define OFF_EIDS ((size_t)671315968)

typedef float f4 __attribute__((ext_vector_type(4)));

static __device__ __forceinline__ float f32(double d) { return (float)d; }

__device__ float g_r[NND], g_phi[NND], g_z[NND], g_st[NND], g_trk[NND], g_io[NND];
__device__ short g_ei[MAXE], g_ej[MAXE];
__device__ int   g_estart[NND + 1];
__device__ float g_dxn[MAXE], g_dyn[MAXE], g_dzn[MAXE], g_iop[MAXE], g_ioc[MAXE];
__device__ int   g_keep[MAXE], g_istrue[MAXE], g_jn[MAXE];
__device__ int   g_cnt2[MAXE], g_off2[MAXE];
__device__ int   g_nedges;

// ---------------- kSid: super_ids default = -2 (kD overwrites kept slots). ~3 us.
__global__ __launch_bounds__(256) void kSid(float* __restrict__ out) {
    int i = blockIdx.x * 256 + threadIdx.x;     // 32768 float4s
    const f4 m = {-2.f, -2.f, -2.f, -2.f};
    ((f4*)(out + OFF_SIDS))[i] = m;
}

// ---------------- kA1: node features + edge offsets + ordered edge list (1 block)
__global__ __launch_bounds__(512) void kA1(const float* __restrict__ ev) {
    __shared__ float s_st[NND];
    __shared__ int   s_scan[NND];
    int t = threadIdx.x;
    float stv = 0.0f;
    if (t < NND) {
        float x = ev[t * 7 + 1], y = ev[t * 7 + 2];
        g_r[t]   = sqrtf(__fadd_rn(__fmul_rn(x, x), __fmul_rn(y, y)));
        g_phi[t] = atan2f(x, y);           // reference: arctan2(x, y)
        g_z[t]   = ev[t * 7 + 3];
        stv      = ev[t * 7 + 4];
        g_st[t]  = stv;  s_st[t] = stv;
        g_trk[t] = ev[t * 7 + 5];
        g_io[t]  = ev[t * 7 + 6];
    }
    __syncthreads();
    int cnt = 0;
    if (t < NND) {
        float target = stv + 1.0f;
        for (int j = 0; j < NND; ++j) cnt += (s_st[j] == target) ? 1 : 0;
        s_scan[t] = cnt;
    }
    __syncthreads();
    for (int off = 1; off < NND; off <<= 1) {   // inclusive scan over 420
        int v = 0;
        if (t < NND && t >= off) v = s_scan[t - off];
        __syncthreads();
        if (t < NND) s_scan[t] += v;
        __syncthreads();
    }
    if (t < NND) {
        int excl = s_scan[t] - cnt;
        g_estart[t] = excl > MAXE ? MAXE : excl;
        int k = excl;
        float target = stv + 1.0f;
        for (int j = 0; j < NND; ++j) {
            if (s_st[j] == target) {
                if (k < MAXE) { g_ei[k] = (short)t; g_ej[k] = (short)j; }
                ++k;
            }
        }
        if (t == NND - 1) {
            g_nedges = s_scan[t] > MAXE ? MAXE : s_scan[t];
            g_estart[NND] = g_nedges;
        }
    }
}

// ---------------- kA2: per-edge features + small outputs (10 blocks x 512)
__global__ __launch_bounds__(512) void kA2(float* __restrict__ out) {
    __shared__ float s_r[NND], s_phi[NND], s_z[NND], s_st[NND], s_trk[NND], s_io[NND];
    int t = threadIdx.x;
    for (int n = t; n < NND; n += 512) {
        s_r[n] = g_r[n]; s_phi[n] = g_phi[n]; s_z[n] = g_z[n];
        s_st[n] = g_st[n]; s_trk[n] = g_trk[n]; s_io[n] = g_io[n];
    }
    __syncthreads();

    const float PI_F  = f32(3.141592653589793);
    const float TPI_F = f32(6.283185307179586);
    const float LO1 = -3.15f, SPAN1 = 3.15f + 3.15f;   // exact f32 of C_HI-C_LO
    const float LO2 = -2386.0f, SPAN2 = 4772.0f;
    const float SPAN0 = 312.0f;

    int k = blockIdx.x * 512 + t;
    if (k >= MAXE) return;
    int ne = g_nedges;
    bool valid = (k < ne);
    int i = valid ? (int)g_ei[k] : 0;
    int j = valid ? (int)g_ej[k] : 0;

    float phip = s_phi[i], phic = s_phi[j];
    float zp = s_z[i], zc = s_z[j];
    float rp = s_r[i], rc = s_r[j];
    float iop = s_io[i], ioc = s_io[j];
    int istrue = (s_trk[i] == s_trk[j]) ? 1 : 0;

    float d = __fsub_rn(phic, phip);
    if (d >  PI_F) d = __fsub_rn(d, TPI_F);
    if (d < -PI_F) d = __fadd_rn(d, TPI_F);

    float dzv = __fsub_rn(zc, zp);
    float dxv = __fsub_rn(rc, rp);
    float dxn = __fdiv_rn(__fmul_rn(2.0f, dxv), SPAN0);
    float dyn = __fdiv_rn(__fmul_rn(2.0f, d),   SPAN1);
    float dzn = __fdiv_rn(__fmul_rn(2.0f, dzv), SPAN2);

    bool keep = valid && (dyn > -10.0f) && (dyn < 10.0f)
                      && (dzn > -10.0f) && (dzn < 10.0f);

    float ypn = __fsub_rn(__fdiv_rn(__fmul_rn(2.0f, __fsub_rn(phip, LO1)), SPAN1), 1.0f);
    float ycn = __fsub_rn(__fdiv_rn(__fmul_rn(2.0f, __fsub_rn(phic, LO1)), SPAN1), 1.0f);
    float zpn = __fsub_rn(__fdiv_rn(__fmul_rn(2.0f, __fsub_rn(zp, LO2)), SPAN2), 1.0f);
    float zcn = __fsub_rn(__fdiv_rn(__fmul_rn(2.0f, __fsub_rn(zc, LO2)), SPAN2), 1.0f);
    float ez  = __fdiv_rn(__fadd_rn(s_st[i], 1.0f), 35.0f);

    size_t oX = OFF_X + (size_t)k * 5;
    out[oX + 0] = keep ? ypn : 0.0f;
    out[oX + 1] = keep ? ycn : 0.0f;
    out[oX + 2] = keep ? zpn : 0.0f;
    out[oX + 3] = keep ? zcn : 0.0f;
    out[oX + 4] = keep ? ez  : 0.0f;

    out[OFF_NIDX + (size_t)k] = keep ? (float)k : -1.0f;
    size_t oE = OFF_EIDS + (size_t)k * 3;
    out[oE + 0] = keep ? iop : -1.0f;
    out[oE + 1] = keep ? ioc : -1.0f;
    out[oE + 2] = keep ? (float)k : -1.0f;

    g_dxn[k] = dxn; g_dyn[k] = dyn; g_dzn[k] = dzn;
    g_iop[k] = iop; g_ioc[k] = ioc;
    g_keep[k] = keep ? 1 : 0; g_istrue[k] = istrue; g_jn[k] = j;
}

// ---------------- kB: one WAVE per a-edge, lane-parallel over b (1280 blocks)
__global__ __launch_bounds__(256) void kB() {
    int gtid = blockIdx.x * 256 + threadIdx.x;
    int a = gtid >> 6, lane = gtid & 63;
    int c = 0;
    if (g_keep[a]) {                        // wave-uniform
        int jn = g_jn[a];
        int b0 = g_estart[jn], b1 = g_estart[jn + 1];
        float ioca = g_ioc[a];
        float a0 = g_dxn[a], a1 = g_dyn[a], a2 = g_dzn[a];
        for (int cs = b0; cs < b1; cs += 64) {
            int b = cs + lane;
            bool pred = false;
            if (b < b1 && g_keep[b] && (g_iop[b] == ioca)) {
                float d0 = __fsub_rn(a0, g_dxn[b]);
                float d1 = __fsub_rn(a1, g_dyn[b]);
                float d2 = __fsub_rn(a2, g_dzn[b]);
                float w = sqrtf(__fadd_rn(__fadd_rn(__fmul_rn(d0, d0),
                                                    __fmul_rn(d1, d1)),
                                          __fmul_rn(d2, d2)));
                pred = (w < 0.1f);
            }
            c += (int)__popcll(__ballot(pred));
        }
    }
    if (lane == 0) g_cnt2[a] = c;
}

// ---------------- kC: exclusive scan over 5120 counts (1 block)
__global__ __launch_bounds__(1024) void kC() {
    __shared__ int part[1024];
    int t = threadIdx.x;
    int v[5]; int s = 0;
#pragma unroll
    for (int q = 0; q < 5; ++q) { v[q] = g_cnt2[t * 5 + q]; s += v[q]; }
    part[t] = s;
    __syncthreads();
    for (int off = 1; off < 1024; off <<= 1) {
        int x = (t >= off) ? part[t - off] : 0;
        __syncthreads();
        part[t] += x;
        __syncthreads();
    }
    int run = part[t] - s;
#pragma unroll
    for (int q = 0; q < 5; ++q) { g_off2[t * 5 + q] = run; run += v[q]; }
}

// ---------------- kD: order-preserving emission via ballot prefix (1280 blocks)
__global__ __launch_bounds__(256) void kD(float* __restrict__ out) {
    int gtid = blockIdx.x * 256 + threadIdx.x;
    int a = gtid >> 6, lane = gtid & 63;
    if (!g_keep[a]) return;                 // wave-uniform
    int jn = g_jn[a];
    int b0 = g_estart[jn], b1 = g_estart[jn + 1];
    float ioca = g_ioc[a];
    float a0 = g_dxn[a], a1 = g_dyn[a], a2 = g_dzn[a];
    int ia = g_istrue[a];
    int base = g_off2[a];
    for (int cs = b0; cs < b1; cs += 64) {
        int b = cs + lane;
        bool pred = false;
        if (b < b1 && g_keep[b] && (g_iop[b] == ioca)) {
            float d0 = __fsub_rn(a0, g_dxn[b]);
            float d1 = __fsub_rn(a1, g_dyn[b]);
            float d2 = __fsub_rn(a2, g_dzn[b]);
            float w = sqrtf(__fadd_rn(__fadd_rn(__fmul_rn(d0, d0),
                                                __fmul_rn(d1, d1)),
                                      __fmul_rn(d2, d2)));
            pred = (w < 0.1f);
        }
        unsigned long long mask = __ballot(pred);
        if (pred) {
            int pos = base + (int)__popcll(mask & ((1ull << lane) - 1ull));
            if (pos < MAXS) {
                out[OFF_SUY + (size_t)pos] = (ia && g_istrue[b]) ? 1.0f : 0.0f;
                size_t os = OFF_SIDS + (size_t)pos * 2;
                out[os + 0] = (float)b;     // su_iop = e_index[se]
                out[os + 1] = (float)a;     // su_ioc = e_index[fi]
                out[OFF_RI + (size_t)a * MAXS + (size_t)pos] = 1.0f;
                out[OFF_RO + (size_t)b * MAXS + (size_t)pos] = 1.0f;
            }
        }
        base += (int)__popcll(mask);
    }
}

extern "C" void kernel_launch(void* const* d_in, const int* in_sizes, int n_in,
                              void* d_out, int out_size, void* d_ws, size_t ws_size,
                              hipStream_t stream) {
    const float* ev = (const float*)d_in[0];
    float* out = (float*)d_out;

    // Runtime fill path measured at 6.1-6.4 TB/s — custom fills (R2/R3/R5) were
    // all slower. The 2.685 GB zero-write is mandatory (d_out is re-poisoned
    // to 0xAA before every timed launch).
    hipMemsetAsync(d_out, 0, (size_t)out_size * sizeof(float), stream);
    hipLaunchKernelGGL(kSid, dim3((MAXS * 2 / 4) / 256), dim3(256), 0, stream, out);
    hipLaunchKernelGGL(kA1, dim3(1), dim3(512), 0, stream, ev);
    hipLaunchKernelGGL(kA2, dim3((MAXE + 511) / 512), dim3(512), 0, stream, out);
    hipLaunchKernelGGL(kB, dim3(MAXE * 64 / 256), dim3(256), 0, stream);
    hipLaunchKernelGGL(kC, dim3(1), dim3(1024), 0, stream);
    hipLaunchKernelGGL(kD, dim3(MAXE * 64 / 256), dim3(256), 0, stream, out);
}